// Round 9
// baseline (138.093 us; speedup 1.0000x reference)
//
#include <hip/hip_runtime.h>
#include <cstdint>

#define NB1 8192
#define NB2 8192
#define DDIM 128
#define KROW 256           // stored row: [hi(128) | lo(128)] f16
#define NSTEP 12           // virtual K = 384 (hi*hi + lo*hi + hi*lo), 32 f16/step

using half8   = __attribute__((ext_vector_type(8))) _Float16;
using half4   = __attribute__((ext_vector_type(4))) _Float16;
using float4v = __attribute__((ext_vector_type(4))) float;

typedef __attribute__((address_space(3))) void       lds_void;
typedef const __attribute__((address_space(1))) void glb_void;

__device__ inline unsigned long long packkey(float v, int j) {
  unsigned u = __float_as_uint(v);
  u = (u & 0x80000000u) ? ~u : (u | 0x80000000u);  // monotone float->uint
  return ((unsigned long long)u << 32) | (unsigned)j;
}

// virtual kt -> source 32-f16 chunk index within the [hi|lo] row
__device__ __forceinline__ int a_src(int kt) { return (kt < 8) ? kt : kt - 8; } // hi,lo,hi
__device__ __forceinline__ int b_src(int kt) { return (kt < 4) ? kt : kt - 4; } // hi,hi,lo

// ---------------------------------------------------------------------------
// Kernel 0: fp32 -> f16 hi/lo split (row = [hi|lo], 256 f16) + squared norms
// + init packed argmin keys. One wave per 2 rows; float4 loads, half4 stores.
// ---------------------------------------------------------------------------
__global__ __launch_bounds__(256) void convert_kernel(
    const float* __restrict__ d1, const float* __restrict__ d2,
    _Float16* __restrict__ A2, _Float16* __restrict__ B2,
    float* __restrict__ asq, float* __restrict__ bsq,
    unsigned long long* __restrict__ packed) {
  int gid  = blockIdx.x * 256 + threadIdx.x;
  int wv   = gid >> 6;
  int lane = gid & 63;
  int rowc = 2 * wv + (lane >> 5);
  bool isA = rowc < NB1;
  const float* src = isA ? d1 : d2;
  int row = isA ? rowc : rowc - NB1;
  int k4  = (lane & 31) * 4;

  float4 v = *(const float4*)&src[row * DDIM + k4];
  _Float16 h0 = (_Float16)v.x, h1 = (_Float16)v.y;
  _Float16 h2 = (_Float16)v.z, h3 = (_Float16)v.w;
  half4 hh = {h0, h1, h2, h3};
  half4 ll = {(_Float16)(v.x - (float)h0), (_Float16)(v.y - (float)h1),
              (_Float16)(v.z - (float)h2), (_Float16)(v.w - (float)h3)};

  _Float16* dst = (isA ? A2 : B2) + (size_t)row * KROW;
  *(half4*)&dst[k4]       = hh;
  *(half4*)&dst[128 + k4] = ll;

  float s = v.x * v.x + v.y * v.y + v.z * v.z + v.w * v.w;
  #pragma unroll
  for (int off = 16; off > 0; off >>= 1) s += __shfl_xor(s, off, 64);
  if ((lane & 31) == 0) (isA ? asq : bsq)[row] = s;

  if (gid < NB1) packed[gid] = 0xFFFFFFFFFFFFFFFFull;  // +inf key
}

// ---------------------------------------------------------------------------
// Kernel 1: MFMA GEMM (virtual K=384 f16, fp32 acc) + fused row argmin.
// 256x256 tile, 8 waves (4Mx2N), 4x8 mfma_f32_16x16x32_f16 per wave.
// Round-9: A BYPASSES LDS. Diagnosis: per-step LDS-unit traffic (frag reads
// 96 KB + staging writes 32 KB = 128 KB ~ 1100-1540 cyc) is co-equal with
// the MFMA floor (1242 cyc) and the lockstep barrier serializes them
// (measured 2950 cyc/step). A-fragments have only 2x cross-wave reuse and
// A2 is L2-resident, so each wave loads af DIRECTLY global->VGPR, one step
// ahead (afn set = 16 VGPR; fits the 128-VGPR half, unlike the 64-VGPR bf
// dbuf of R5-R7). B keeps LDS staging (4x reuse). LDS traffic 128->80 KB;
// MFMA's in-step wait chain drops 12->8 ds_reads; A-LDS freed (ring-3 B =
// 48 KB; block LDS 66 KB).
// Ledger (per-wave VMEM issue order, compiler-fenced):
//   step k issues [afn(k+1) x4 | stB(k+2) x2]; top-of-step vmcnt(2) drains
//   afn(k) (MFMA k operand) + stB(k) (bf reads), keeps stB(k+1) in flight.
//   Prologue [afA(0) x4 | stB(0) x2 | stB(1) x2] + vmcnt(2). Tail 2,...,2,0.
//   stB(k+2) -> buf (k+2)%3: its previous readers (step k-1) finished
//   before this step's barrier. Compiler additionally tracks afn register
//   deps with its own counted vmcnt — harmless double cover.
// T2 swizzle on B unchanged (verified SQ_LDS_BANK_CONFLICT = 0).
// ---------------------------------------------------------------------------
__global__ __launch_bounds__(512, 2) void mfma_match_kernel(
    const _Float16* __restrict__ A2, const _Float16* __restrict__ B2,
    const float* __restrict__ bsq, unsigned long long* __restrict__ packed) {
  __shared__ unsigned long long smem[8448];  // 67584 B: B-ring 48K | epi table
  _Float16* SB = (_Float16*)smem;            // B buf b at SB + b*8192 (16 KB)

  const int t    = threadIdx.x;
  const int lane = t & 63;
  const int wid  = t >> 6;           // 0..7
  const int wm   = wid >> 1;         // 0..3 : 64-row band of A
  const int wn   = wid & 1;          // 0..1 : 128-col band of B
  const int lx   = lane & 15, q = lane >> 4;

  // XCD swizzle: 1024 blocks over 8 XCDs; per-XCD 16(bx) x 8(by) rectangle
  // -> resident set 16 A-panels (2 MB) + 8 B-panels (1 MB) < 4 MB L2.
  const int id  = blockIdx.x;
  const int xcd = id & 7, kk = id >> 3;          // kk 0..127
  const int bx = (xcd & 1) * 16 + (kk & 15);
  const int by = (xcd >> 1) * 8 + (kk >> 4);
  const int row0 = bx * 256, col0 = by * 256;

  // B staging geometry (R1-verified): call covers 128 rows; thread t ->
  // row t>>2, LDS slot t&3; source chunk = inverse swizzle (slot-(row>>1))&3.
  const int rstg  = t >> 2;
  const int cslot = t & 3;
  const int cc    = (cslot - (rstg >> 1)) & 3;   // same for both 128-row halves
  const _Float16* gB0 = B2 + (size_t)(col0 + rstg) * KROW + cc * 8;

  // Per-lane A source: row = row0 + wm*64 + 16r + lx, bytes q*16 within chunk.
  const _Float16* pAq = A2 + (size_t)(row0 + wm * 64 + lx) * KROW + q * 8;

  float4v acc[4][8];
  #pragma unroll
  for (int m = 0; m < 4; ++m)
    #pragma unroll
    for (int c = 0; c < 8; ++c) acc[m][c] = (float4v){0.f, 0.f, 0.f, 0.f};

  auto stageB = [&](int kt, int buf) {
    const int ko = b_src(kt) * 32;
    __builtin_amdgcn_global_load_lds((glb_void*)(gB0 + ko),
        (lds_void*)(SB + buf * 8192 + wid * 512), 16, 0, 0);
    __builtin_amdgcn_global_load_lds((glb_void*)(gB0 + 128 * KROW + ko),
        (lds_void*)(SB + buf * 8192 + 4096 + wid * 512), 16, 0, 0);
  };

  half8 afA[4], afB[4], bf[8];

  auto ldA = [&](int kt, half8 (&af)[4]) {   // 4 global (L2) 16B loads
    const int ko = a_src(kt) * 32;
    #pragma unroll
    for (int r = 0; r < 4; ++r)
      af[r] = *(const half8*)&pAq[(size_t)(16 * r) * KROW + ko];
  };

  const int sw = ((q + (lx >> 1)) & 3) * 8;   // bank-swizzled chunk offset
  auto rdB = [&](int buf) {                   // 8 conflict-free ds_read_b128
    const _Float16* Bb = SB + buf * 8192;
    #pragma unroll
    for (int c = 0; c < 8; ++c)
      bf[c] = *(const half8*)&Bb[(wn * 128 + 16 * c + lx) * 32 + sw];
  };

  auto mm = [&](half8 (&af)[4]) {
    __builtin_amdgcn_s_setprio(1);
    #pragma unroll
    for (int m = 0; m < 4; ++m)
      #pragma unroll
      for (int c = 0; c < 8; ++c)
        acc[m][c] = __builtin_amdgcn_mfma_f32_16x16x32_f16(
            af[m], bf[c], acc[m][c], 0, 0, 0);
    __builtin_amdgcn_s_setprio(0);
  };

#define FENCE() asm volatile("" ::: "memory")

  // Prologue: afA(0) + stB(0) + stB(1); drain afA+stB(0), keep stB(1).
  ldA(0, afA);
  FENCE();
  stageB(0, 0); stageB(1, 1);
  asm volatile("s_waitcnt vmcnt(2)" ::: "memory");
  __builtin_amdgcn_s_barrier();
  FENCE();

  // MS = af set for MFMA(K); RS = set receiving afn(K+1).
#define STEP(K, VM, MS, RS, DOA, DOB)                                 \
  do {                                                                \
    if constexpr ((K) > 0) {                                          \
      asm volatile("s_waitcnt vmcnt(" VM ")" ::: "memory");           \
      __builtin_amdgcn_s_barrier();                                   \
      FENCE();                                                        \
    }                                                                 \
    if constexpr (DOA) ldA((K) + 1, af##RS);                          \
    FENCE();                                                          \
    if constexpr (DOB) stageB((K) + 2, ((K) + 2) % 3);                \
    FENCE();                                                          \
    rdB((K) % 3);                                                     \
    mm(af##MS);                                                       \
  } while (0)

  STEP(0,  "2", A, B, true,  true);
  STEP(1,  "2", B, A, true,  true);
  STEP(2,  "2", A, B, true,  true);
  STEP(3,  "2", B, A, true,  true);
  STEP(4,  "2", A, B, true,  true);
  STEP(5,  "2", B, A, true,  true);
  STEP(6,  "2", A, B, true,  true);
  STEP(7,  "2", B, A, true,  true);
  STEP(8,  "2", A, B, true,  true);
  STEP(9,  "2", B, A, true,  true);
  STEP(10, "2", A, B, true,  false);
  STEP(11, "0", B, A, false, false);
#undef STEP

  // ---- Epilogue. C/D layout: col = lane&15, row = q*4 + reg. ----
  __syncthreads();  // all bf reads done before aliasing staging LDS
  const int jc0 = col0 + wn * 128 + lx;
  float bq[8];
  #pragma unroll
  for (int c = 0; c < 8; ++c) bq[c] = bsq[jc0 + 16 * c];

  #pragma unroll
  for (int m = 0; m < 4; ++m) {
    #pragma unroll
    for (int reg = 0; reg < 4; ++reg) {
      float bv = 1e30f; int bj = 0;
      #pragma unroll
      for (int c = 0; c < 8; ++c) {  // j ascending -> strict < keeps min j
        float val = fmaf(-2.f, acc[m][c][reg], bq[c]);
        if (val < bv) { bv = val; bj = jc0 + 16 * c; }
      }
      const int mrow = wm * 64 + 16 * m + 4 * q + reg;
      smem[mrow * 33 + wn * 16 + lx] = packkey(bv, bj);  // pad-33: no 16-way
    }
  }
  __syncthreads();
  if (t < 256) {
    unsigned long long best = ~0ull;
    #pragma unroll
    for (int c = 0; c < 32; ++c) {   // rotated read: spread banks across rows
      unsigned long long kx = smem[t * 33 + ((2 * t + c) & 31)];
      if (kx < best) best = kx;
    }
    // Pre-filter: packed[] is monotone-decreasing, so a stale read only
    // causes a harmless extra atomic, never a lost minimum.
    unsigned long long cur = packed[row0 + t];
    if (best < cur) atomicMin(&packed[row0 + t], best);
  }
}

// ---------------------------------------------------------------------------
// Kernel 2: decode packed keys, write outputs.
// ---------------------------------------------------------------------------
__global__ __launch_bounds__(256) void out_kernel(
    const unsigned long long* __restrict__ packed,
    const float* __restrict__ asq, float* __restrict__ out) {
  int r = blockIdx.x * 256 + threadIdx.x;
  unsigned long long best = packed[r];
  unsigned u = (unsigned)(best >> 32);
  u = (u & 0x80000000u) ? (u & 0x7fffffffu) : ~u;   // invert monotone map
  float val  = __uint_as_float(u);
  float dist = sqrtf(fmaxf(asq[r] + val, 0.f));
  int j = (int)(unsigned)(best & 0xffffffffu);
  out[r]               = dist;
  out[NB1 + 2 * r]     = (float)r;
  out[NB1 + 2 * r + 1] = (float)j;
}

extern "C" void kernel_launch(void* const* d_in, const int* in_sizes, int n_in,
                              void* d_out, int out_size, void* d_ws, size_t ws_size,
                              hipStream_t stream) {
  const float* d1 = (const float*)d_in[0];
  const float* d2 = (const float*)d_in[1];
  float* out = (float*)d_out;

  char* w = (char*)d_ws;
  float* asq = (float*)w;                                   // 32 KB
  float* bsq = (float*)(w + 32768);                         // 32 KB
  _Float16* A2 = (_Float16*)(w + 65536);                    // 4 MB
  _Float16* B2 = (_Float16*)(w + 65536 + 4194304);          // 4 MB
  unsigned long long* packed =
      (unsigned long long*)(w + 65536 + 2 * 4194304);       // 64 KB

  convert_kernel<<<(NB1 + NB2) / 8, 256, 0, stream>>>(
      d1, d2, A2, B2, asq, bsq, packed);

  mfma_match_kernel<<<(NB1 / 256) * (NB2 / 256), 512, 0, stream>>>(
      A2, B2, bsq, packed);

  out_kernel<<<NB1 / 256, 256, 0, stream>>>(packed, asq, out);
}